// Round 4
// baseline (11151.807 us; speedup 1.0000x reference)
//
#include <hip/hip_runtime.h>
#include <hip/hip_bf16.h>

typedef __attribute__((ext_vector_type(4))) float f32x4;
typedef __attribute__((ext_vector_type(8))) short short8;
typedef unsigned short u16;
typedef unsigned long long u64;

constexpr int B = 64, S = 512, KIN = 512, H = 1024;

// ---- workspace layout (bytes) ----
// sync region: 8 group counters, each on its own 128B line
constexpr size_t OFF_CNT   = 0;          // u32[8*32]
constexpr size_t OFF_H0BF  = 4096;
constexpr size_t SZ_HBF    = (size_t)2*2*B*H*2;   // [dir][slot][B][H] bf16
constexpr size_t OFF_H1BF  = OFF_H0BF + SZ_HBF;
constexpr size_t OFF_ZEND  = OFF_H1BF + SZ_HBF;          // zeroed region end
constexpr size_t OFF_XBF   = (OFF_ZEND + 255) & ~(size_t)255;
constexpr size_t SZ_XBF    = (size_t)S*B*KIN*2;          // [t][b][k] bf16
constexpr size_t OFF_WP    = OFF_XBF + SZ_XBF;
constexpr size_t WP_ELEMS0 = (size_t)64*48*1536;         // per layer-0 cell
constexpr size_t WP_ELEMS1 = (size_t)64*48*2048;         // per layer-1 cell

__device__ __forceinline__ u16 f2bf(float v) {
    __hip_bfloat16 h = __float2bfloat16(v);
    return *reinterpret_cast<u16*>(&h);
}

// coherent (agent-scope) 16B h-state read: sees write-through h stores without
// any cache-invalidate fence; immutable data (x, weights) stays L2-cached.
__device__ __forceinline__ short8 ldh16(const u16* p) {
    u64 lo = __hip_atomic_load((const u64*)p,       __ATOMIC_RELAXED, __HIP_MEMORY_SCOPE_AGENT);
    u64 hi = __hip_atomic_load((const u64*)p + 1,   __ATOMIC_RELAXED, __HIP_MEMORY_SCOPE_AGENT);
    union { u64 q[2]; short8 s; } u;
    u.q[0] = lo; u.q[1] = hi;
    return u.s;
}

// Pack weights to bf16, per-block-contiguous [cell][blk][c(48)][K], c: 0-15=r,16-31=z,32-47=n.
// Cell 1 (layer0 backward): fold the feature reversal by reversing w_ih's K axis.
__global__ void pack_w(const float* __restrict__ wi0f, const float* __restrict__ wh0f,
                       const float* __restrict__ wi0b, const float* __restrict__ wh0b,
                       const float* __restrict__ wi1f, const float* __restrict__ wh1f,
                       const float* __restrict__ wi1b, const float* __restrict__ wh1b,
                       u16* __restrict__ wp) {
    int bx = blockIdx.x;
    int cell = bx / (64*48);
    int rem  = bx % (64*48);
    int blk = rem / 48, c = rem % 48;
    int K  = (cell < 2) ? 1536 : 2048;
    int Ki = (cell < 2) ? 512  : 1024;
    int n = (c >> 4)*H + blk*16 + (c & 15);
    const float* wi = (cell==0)?wi0f:(cell==1)?wi0b:(cell==2)?wi1f:wi1b;
    const float* wh = (cell==0)?wh0f:(cell==1)?wh0b:(cell==2)?wh1f:wh1b;
    size_t base = (cell==0)?0:(cell==1)?WP_ELEMS0:(cell==2)?2*WP_ELEMS0:2*WP_ELEMS0+WP_ELEMS1;
    u16* dst = wp + base + ((size_t)blk*48 + c)*K;
    for (int k = threadIdx.x; k < K; k += 256) {
        float v;
        if (k < Ki) v = wi[(size_t)n*Ki + ((cell==1) ? (Ki-1-k) : k)];
        else        v = wh[(size_t)n*H + (k - Ki)];
        dst[k] = f2bf(v);
    }
}

// x (B,S,IN) fp32 -> xbf [t][b][k] bf16
__global__ void conv_x(const float* __restrict__ x, u16* __restrict__ xbf) {
    int t = blockIdx.x >> 6;
    int b = blockIdx.x & 63;
    const float* src = x + ((size_t)b*S + t)*KIN;
    u16* dst = xbf + ((size_t)t*B + b)*KIN;
    for (int k = threadIdx.x; k < KIN; k += 256)
        dst[k] = f2bf(src[k]);
}

struct PArgs {
    const u16* wp;
    const u16* xbf;
    const float* bih0f; const float* bhh0f;
    const float* bih0b; const float* bhh0b;
    const float* bih1f; const float* bhh1f;
    const float* bih1b; const float* bhh1b;
    u16* h0bf; u16* h1bf;
    float* out;    // [B][S][2H]
    float* out2;   // [B][2H]
    unsigned* cnt; // sync region
};

#define MFMA16 __builtin_amdgcn_mfma_f32_16x16x32_bf16

// Persistent cell body, 8 waves/block. Weights live in VGPRs for the whole sequence.
// K split 8-way across waves: wave wv owns windows [wv*NKS, (wv+1)*NKS) of 32 K-elems.
// Cross-wave reduce: 2-stage tree in one 64KB LDS buffer.
// red layout (f32x4 units): slot(0..3)*1024 + gate(0..3)*256 + cix*16 + chunk
template<int NKS, int NIW, int K, int LDIN, bool INATM>
__device__ __forceinline__ void run_cell(const PArgs& a, const int cell,
        const u16* __restrict__ wblk, const float* __restrict__ bih,
        const float* __restrict__ bhh, f32x4* red) {
    const int tid  = threadIdx.x;
    const int lane = tid & 63;
    const int wv   = tid >> 6;       // wave id 0..7 = K-slice owner
    const int q    = lane >> 4;      // fragment k-subgroup
    const int cix  = lane & 15;
    const int qo   = q * 8;
    const int blk  = blockIdx.x & 63;
    const int j0   = blk * 16;
    const int dir  = cell & 1;

    // epilogue mapping: one col, 4 consecutive rows per thread (mod 256)
    const int col = tid & 15;
    const int rq  = (tid >> 4) & 15;
    const int r0  = rq * 4;
    const int jl  = j0 + col;
    const bool hPath = (tid < 256);      // waves 0-3: h update; waves 4-7: out stores
    const float br  = bih[jl]       + bhh[jl];
    const float bz  = bih[H + jl]   + bhh[H + jl];
    const float bin = bih[2*H + jl];
    const float bhn = bhh[2*H + jl];

    u16* myh0b = a.h0bf + (size_t)dir*2*B*H;
    u16* myh1b = a.h1bf + (size_t)dir*2*B*H;

    // ---- barrier: 8 group counter lines, poll all 8 ----
    const int grp = blockIdx.x & 7;
    unsigned* gcnt = a.cnt + (size_t)grp*32;

    // ---- load this wave's weight slice into registers (once) ----
    short8 wr[NKS], wz[NKS], wn[NKS];
    #pragma unroll
    for (int i = 0; i < NKS; ++i) {
        const int kwg = wv*NKS + i;
        wr[i] = *(const short8*)(wblk + (size_t)cix*K      + kwg*32 + qo);
        wz[i] = *(const short8*)(wblk + (size_t)(16+cix)*K + kwg*32 + qo);
        wn[i] = *(const short8*)(wblk + (size_t)(32+cix)*K + kwg*32 + qo);
    }

    // per-thread h_prev mirror. Waves 0-3 use it for the h write path; waves 4-7
    // maintain an identical copy (same LDS sums -> same hn) for the out path.
    float hp[4] = {0.f, 0.f, 0.f, 0.f};

    for (int tick = 0; tick <= S; ++tick) {
        const bool active = (cell < 2) ? (tick < S) : (tick >= 1);
        const int t = (cell < 2) ? tick : (tick - 1);
        if (active) {
            const int sprev = (t + 1) & 1, scur = t & 1;
            const u16* aIn;
            const u16* aHid;
            if (cell < 2) { aIn = a.xbf + (size_t)t*B*KIN;   aHid = myh0b + (size_t)sprev*B*H; }
            else          { aIn = myh0b + (size_t)scur*B*H;  aHid = myh1b + (size_t)sprev*B*H; }
            const u16* rowIn[4]; const u16* rowHid[4];
            #pragma unroll
            for (int m = 0; m < 4; ++m) {
                rowIn[m]  = aIn  + (size_t)(m*16 + cix)*LDIN + qo;
                rowHid[m] = aHid + (size_t)(m*16 + cix)*H    + qo;
            }
            f32x4 aR[4], aZ[4], aNI[4], aNH[4];
            #pragma unroll
            for (int m = 0; m < 4; ++m) {
                aR[m]  = f32x4{0,0,0,0}; aZ[m]  = f32x4{0,0,0,0};
                aNI[m] = f32x4{0,0,0,0}; aNH[m] = f32x4{0,0,0,0};
            }
            #pragma unroll
            for (int i = 0; i < NKS; ++i) {
                const int kwg = wv*NKS + i;
                if (kwg < NIW) {
                    #pragma unroll
                    for (int m = 0; m < 4; ++m) {
                        short8 af;
                        if (INATM) af = ldh16(rowIn[m] + (size_t)kwg*32);
                        else       af = *(const short8*)(rowIn[m] + (size_t)kwg*32);
                        aR[m]  = MFMA16(af, wr[i], aR[m],  0,0,0);
                        aZ[m]  = MFMA16(af, wz[i], aZ[m],  0,0,0);
                        aNI[m] = MFMA16(af, wn[i], aNI[m], 0,0,0);
                    }
                } else {
                    #pragma unroll
                    for (int m = 0; m < 4; ++m) {
                        short8 af = ldh16(rowHid[m] + (size_t)(kwg - NIW)*32);
                        aR[m]  = MFMA16(af, wr[i], aR[m],  0,0,0);
                        aZ[m]  = MFMA16(af, wz[i], aZ[m],  0,0,0);
                        aNH[m] = MFMA16(af, wn[i], aNH[m], 0,0,0);
                    }
                }
            }
            // ---- stage 1: waves 4-7 write partials to slot wv-4 ----
            if (wv >= 4) {
                f32x4* pw = red + (size_t)(wv - 4)*1024;
                #pragma unroll
                for (int m = 0; m < 4; ++m) {
                    const int cbase = cix*16;
                    const int csw   = (m*4 + q) ^ (cix & 7);
                    pw[0*256 + cbase + csw] = aR[m];
                    pw[1*256 + cbase + csw] = aZ[m];
                    pw[2*256 + cbase + csw] = aNI[m];
                    pw[3*256 + cbase + csw] = aNH[m];
                }
            }
            __syncthreads();
            // ---- stage 2: waves 0-3 fold partner partials, write 2-way sums ----
            if (wv < 4) {
                f32x4* pw = red + (size_t)wv*1024;
                #pragma unroll
                for (int m = 0; m < 4; ++m) {
                    const int cbase = cix*16;
                    const int csw   = (m*4 + q) ^ (cix & 7);
                    aR[m]  += pw[0*256 + cbase + csw];
                    aZ[m]  += pw[1*256 + cbase + csw];
                    aNI[m] += pw[2*256 + cbase + csw];
                    aNH[m] += pw[3*256 + cbase + csw];
                    pw[0*256 + cbase + csw] = aR[m];
                    pw[1*256 + cbase + csw] = aZ[m];
                    pw[2*256 + cbase + csw] = aNI[m];
                    pw[3*256 + cbase + csw] = aNH[m];
                }
            }
            __syncthreads();
            // ---- stage 3: final 4-way sum + elementwise ----
            // waves 0-3: h update + coherent h store (critical path)
            // waves 4-7: duplicate elementwise (own hp mirror), nontemporal out stores
            if (hPath || cell >= 2) {
                f32x4 sR = {0,0,0,0}, sZ = {0,0,0,0}, sNI = {0,0,0,0}, sNH = {0,0,0,0};
                const int cidx = col*16 + (rq ^ (col & 7));
                #pragma unroll
                for (int ww = 0; ww < 4; ++ww) {
                    const f32x4* pr = red + (size_t)ww*1024;
                    sR  += pr[0*256 + cidx];
                    sZ  += pr[1*256 + cidx];
                    sNI += pr[2*256 + cidx];
                    sNH += pr[3*256 + cidx];
                }
                u16* hcurb = ((cell < 2) ? myh0b : myh1b) + (size_t)scur*B*H;
                #pragma unroll
                for (int v = 0; v < 4; ++v) {
                    float r  = 1.f/(1.f + __expf(-(sR[v] + br)));
                    float z  = 1.f/(1.f + __expf(-(sZ[v] + bz)));
                    float xn = (sNI[v] + bin) + r*(sNH[v] + bhn);
                    float e2 = __expf(2.f*xn);
                    float n  = 1.f - 2.f/(e2 + 1.f);          // tanh, no inf/inf
                    float hn = (1.f - z)*n + z*hp[v];
                    hp[v] = hn;                                // BOTH paths keep h_prev current
                    if (hPath) {
                        // write-through (agent scope): no writeback fence ever needed
                        __hip_atomic_store(&hcurb[(size_t)(r0 + v)*H + jl], f2bf(hn),
                                           __ATOMIC_RELAXED, __HIP_MEMORY_SCOPE_AGENT);
                    } else {  // cell >= 2, waves 4-7
                        __builtin_nontemporal_store(hn, &a.out[((size_t)(r0+v)*S + t)*(2*H) + dir*H + jl]);
                        if (t == S-1)
                            __builtin_nontemporal_store(hn, &a.out2[(size_t)(r0+v)*(2*H) + dir*H + jl]);
                    }
                }
            }
        }
        // ---- grid barrier: drain ALL waves' stores, RMW own group line, poll all 8 ----
        if (tick < S) {
            __syncthreads();   // every wave's h write-through stores drained (vmcnt(0) @ s_barrier)
            if (tid == 0) {
                asm volatile("s_waitcnt vmcnt(0)" ::: "memory");
                __hip_atomic_fetch_add(gcnt, 1u, __ATOMIC_RELAXED, __HIP_MEMORY_SCOPE_AGENT);
                const unsigned tgt = 32u*(unsigned)(tick + 1);
                for (;;) {
                    bool ok = true;
                    #pragma unroll
                    for (int f = 0; f < 8; ++f)
                        ok &= (__hip_atomic_load(a.cnt + (size_t)f*32, __ATOMIC_RELAXED,
                                                 __HIP_MEMORY_SCOPE_AGENT) >= tgt);
                    if (ok) break;
                    __builtin_amdgcn_s_sleep(2);
                }
            }
            __syncthreads();
        }
    }
}

// 256 blocks x 512 threads, persistent. block = (cell<<6)|blk; cell 0=0f,1=0b,2=1f,3=1b.
// Tick tau: layer0 computes t=tau (tau<S); layer1 computes t=tau-1 (tau>=1). One barrier/tick.
__launch_bounds__(512, 2)
__global__ void gru_persist(PArgs a) {
    __shared__ __align__(16) f32x4 red[4096];   // 64 KB, 2-stage reduce buffer
    const int cell = blockIdx.x >> 6;
    const int blk  = blockIdx.x & 63;
    if (cell == 0) {
        run_cell<6,16,1536,KIN,false>(a, 0, a.wp + (size_t)blk*48*1536,
                                      a.bih0f, a.bhh0f, red);
    } else if (cell == 1) {
        run_cell<6,16,1536,KIN,false>(a, 1, a.wp + WP_ELEMS0 + (size_t)blk*48*1536,
                                      a.bih0b, a.bhh0b, red);
    } else if (cell == 2) {
        run_cell<8,32,2048,H,true>(a, 2, a.wp + 2*WP_ELEMS0 + (size_t)blk*48*2048,
                                   a.bih1f, a.bhh1f, red);
    } else {
        run_cell<8,32,2048,H,true>(a, 3, a.wp + 2*WP_ELEMS0 + WP_ELEMS1 + (size_t)blk*48*2048,
                                   a.bih1b, a.bhh1b, red);
    }
}

extern "C" void kernel_launch(void* const* d_in, const int* in_sizes, int n_in,
                              void* d_out, int out_size, void* d_ws, size_t ws_size,
                              hipStream_t stream) {
    const float* x    = (const float*)d_in[0];
    const float* wi0f = (const float*)d_in[1];
    const float* wh0f = (const float*)d_in[2];
    const float* bi0f = (const float*)d_in[3];
    const float* bh0f = (const float*)d_in[4];
    const float* wi0b = (const float*)d_in[5];
    const float* wh0b = (const float*)d_in[6];
    const float* bi0b = (const float*)d_in[7];
    const float* bh0b = (const float*)d_in[8];
    const float* wi1f = (const float*)d_in[9];
    const float* wh1f = (const float*)d_in[10];
    const float* bi1f = (const float*)d_in[11];
    const float* bh1f = (const float*)d_in[12];
    const float* wi1b = (const float*)d_in[13];
    const float* wh1b = (const float*)d_in[14];
    const float* bi1b = (const float*)d_in[15];
    const float* bh1b = (const float*)d_in[16];

    char* ws = (char*)d_ws;
    hipMemsetAsync(ws, 0, OFF_ZEND, stream);   // barrier counters + h states = 0

    u16* xbf = (u16*)(ws + OFF_XBF);
    u16* wp  = (u16*)(ws + OFF_WP);

    pack_w<<<4*64*48, 256, 0, stream>>>(wi0f, wh0f, wi0b, wh0b, wi1f, wh1f, wi1b, wh1b, wp);
    conv_x<<<S*B, 256, 0, stream>>>(x, xbf);

    PArgs a;
    a.wp = wp; a.xbf = xbf;
    a.bih0f = bi0f; a.bhh0f = bh0f; a.bih0b = bi0b; a.bhh0b = bh0b;
    a.bih1f = bi1f; a.bhh1f = bh1f; a.bih1b = bi1b; a.bhh1b = bh1b;
    a.h0bf = (u16*)(ws + OFF_H0BF); a.h1bf = (u16*)(ws + OFF_H1BF);
    a.out  = (float*)d_out;
    a.out2 = (float*)d_out + (size_t)B*S*2*H;
    a.cnt  = (unsigned*)(ws + OFF_CNT);
    gru_persist<<<256, 512, 0, stream>>>(a);
}

// Round 5
// 7783.281 us; speedup vs baseline: 1.4328x; 1.4328x over previous
//
#include <hip/hip_runtime.h>
#include <hip/hip_bf16.h>

typedef __attribute__((ext_vector_type(4))) float f32x4;
typedef __attribute__((ext_vector_type(8))) short short8;
typedef unsigned short u16;

constexpr int B = 64, S = 512, KIN = 512, H = 1024;
constexpr int R0 = 4;                         // h0 ring depth (layer0 run-ahead 3)

// ---- workspace layout (bytes) ----
// sync region: 4 cells x 8 progress lines, each on its own 128B line
constexpr size_t OFF_CNT   = 0;               // u32[32*32]
constexpr size_t OFF_H0BF  = 4096;            // [dir][slot(R0)][B][H] bf16
constexpr size_t SZ_H0BF   = (size_t)2*R0*B*H*2;
constexpr size_t OFF_H1BF  = OFF_H0BF + SZ_H0BF;      // [dir][slot(2)][B][H] bf16
constexpr size_t SZ_H1BF   = (size_t)2*2*B*H*2;
constexpr size_t OFF_ZEND  = OFF_H1BF + SZ_H1BF;      // zeroed region end
constexpr size_t OFF_XBF   = (OFF_ZEND + 255) & ~(size_t)255;
constexpr size_t SZ_XBF    = (size_t)S*B*KIN*2;       // [t][b][k] bf16
constexpr size_t OFF_WP    = OFF_XBF + SZ_XBF;
constexpr size_t WP_ELEMS0 = (size_t)64*48*1536;      // per layer-0 cell
constexpr size_t WP_ELEMS1 = (size_t)64*48*2048;      // per layer-1 cell

__device__ __forceinline__ u16 f2bf(float v) {
    __hip_bfloat16 h = __float2bfloat16(v);
    return *reinterpret_cast<u16*>(&h);
}

// Pack weights to bf16, per-block-contiguous [cell][blk][c(48)][K], c: 0-15=r,16-31=z,32-47=n.
// Cell 1 (layer0 backward): fold the feature reversal by reversing w_ih's K axis.
__global__ void pack_w(const float* __restrict__ wi0f, const float* __restrict__ wh0f,
                       const float* __restrict__ wi0b, const float* __restrict__ wh0b,
                       const float* __restrict__ wi1f, const float* __restrict__ wh1f,
                       const float* __restrict__ wi1b, const float* __restrict__ wh1b,
                       u16* __restrict__ wp) {
    int bx = blockIdx.x;
    int cell = bx / (64*48);
    int rem  = bx % (64*48);
    int blk = rem / 48, c = rem % 48;
    int K  = (cell < 2) ? 1536 : 2048;
    int Ki = (cell < 2) ? 512  : 1024;
    int n = (c >> 4)*H + blk*16 + (c & 15);
    const float* wi = (cell==0)?wi0f:(cell==1)?wi0b:(cell==2)?wi1f:wi1b;
    const float* wh = (cell==0)?wh0f:(cell==1)?wh0b:(cell==2)?wh1f:wh1b;
    size_t base = (cell==0)?0:(cell==1)?WP_ELEMS0:(cell==2)?2*WP_ELEMS0:2*WP_ELEMS0+WP_ELEMS1;
    u16* dst = wp + base + ((size_t)blk*48 + c)*K;
    for (int k = threadIdx.x; k < K; k += 256) {
        float v;
        if (k < Ki) v = wi[(size_t)n*Ki + ((cell==1) ? (Ki-1-k) : k)];
        else        v = wh[(size_t)n*H + (k - Ki)];
        dst[k] = f2bf(v);
    }
}

// x (B,S,IN) fp32 -> xbf [t][b][k] bf16
__global__ void conv_x(const float* __restrict__ x, u16* __restrict__ xbf) {
    int t = blockIdx.x >> 6;
    int b = blockIdx.x & 63;
    const float* src = x + ((size_t)b*S + t)*KIN;
    u16* dst = xbf + ((size_t)t*B + b)*KIN;
    for (int k = threadIdx.x; k < KIN; k += 256)
        dst[k] = f2bf(src[k]);
}

struct PArgs {
    const u16* wp;
    const u16* xbf;
    const float* bih0f; const float* bhh0f;
    const float* bih0b; const float* bhh0b;
    const float* bih1f; const float* bhh1f;
    const float* bih1b; const float* bhh1b;
    u16* h0bf; u16* h1bf;
    float* out;    // [B][S][2H]
    float* out2;   // [B][2H]
    unsigned* cnt; // sync region
};

#define MFMA16 __builtin_amdgcn_mfma_f32_16x16x32_bf16

// poll 8 progress lines (one per group of 8 blocks) until all >= tgt
__device__ __forceinline__ void wait8(const unsigned* base, unsigned tgt) {
    for (;;) {
        bool ok = true;
        #pragma unroll
        for (int g = 0; g < 8; ++g)
            ok &= (__hip_atomic_load(base + (size_t)g*32, __ATOMIC_RELAXED,
                                     __HIP_MEMORY_SCOPE_AGENT) >= tgt);
        if (ok) return;
        __builtin_amdgcn_s_sleep(1);
    }
}

// Persistent cell body, 8 waves/block. Weights in VGPRs for the whole sequence.
// Each cell group (64 blocks) runs its OWN t-loop, paced by per-cell progress lines:
//   L0 cell d, tick t: needs own-cell done t-1; if t>=R0, needs L1 cell d done t-R0
//     (anti-overwrite of h0 ring slot). Writes h0[d][t % R0].
//   L1 cell d, tick t: needs own-cell done t-1; needs L0 cell d done t. Writes h1, out[t].
// Coherence: h stores are write-through agent-scope; one acquire fence (tid0) per tick
// invalidates L1/L2 so plain b128 loads see fresh h. Progress via relaxed agent atomics.
template<int NKS, int NIW, int K, int LDIN, bool ISL1>
__device__ __forceinline__ void run_cell(const PArgs& a, const int dir,
        const u16* __restrict__ wblk, const float* __restrict__ bih,
        const float* __restrict__ bhh, f32x4* red) {
    const int tid  = threadIdx.x;
    const int lane = tid & 63;
    const int wv   = tid >> 6;       // wave id 0..7 = K-slice owner
    const int q    = lane >> 4;      // fragment k-subgroup
    const int cix  = lane & 15;
    const int qo   = q * 8;
    const int blk  = blockIdx.x & 63;
    const int j0   = blk * 16;

    // epilogue mapping: one col, 4 consecutive rows per thread (mod 256)
    const int col = tid & 15;
    const int rq  = (tid >> 4) & 15;
    const int r0  = rq * 4;
    const int jl  = j0 + col;
    const bool hPath = (tid < 256);      // waves 0-3: h update; waves 4-7: out stores (L1)
    const float br  = bih[jl]       + bhh[jl];
    const float bz  = bih[H + jl]   + bhh[H + jl];
    const float bin = bih[2*H + jl];
    const float bhn = bhh[2*H + jl];

    u16* myh0 = a.h0bf + (size_t)dir*R0*B*H;
    u16* myh1 = a.h1bf + (size_t)dir*2*B*H;

    // ---- progress lines ----
    const int cell = (ISL1 ? 2 : 0) + dir;
    unsigned* ownL  = a.cnt + (size_t)cell*8*32;
    unsigned* prodL = a.cnt + (size_t)(cell-2)*8*32;   // L1 only
    unsigned* consL = a.cnt + (size_t)(cell+2)*8*32;   // L0 only
    unsigned* myline = ownL + (size_t)(blk & 7)*32;

    // ---- load this wave's weight slice into registers (once) ----
    short8 wr[NKS], wz[NKS], wn[NKS];
    #pragma unroll
    for (int i = 0; i < NKS; ++i) {
        const int kwg = wv*NKS + i;
        wr[i] = *(const short8*)(wblk + (size_t)cix*K      + kwg*32 + qo);
        wz[i] = *(const short8*)(wblk + (size_t)(16+cix)*K + kwg*32 + qo);
        wn[i] = *(const short8*)(wblk + (size_t)(32+cix)*K + kwg*32 + qo);
    }

    // per-thread h_prev mirror; waves 4-7 (L1 out path) keep an identical copy.
    float hp[4] = {0.f, 0.f, 0.f, 0.f};

    for (int t = 0; t < S; ++t) {
        // ---- wait for dependencies, then invalidate caches once ----
        if (tid == 0) {
            wait8(ownL, 8u*(unsigned)t);                       // own cell finished t-1
            if (ISL1)          wait8(prodL, 8u*(unsigned)(t+1));      // h0[t] complete
            else if (t >= R0)  wait8(consL, 8u*(unsigned)(t-(R0-1))); // ring slot free
            __builtin_amdgcn_fence(__ATOMIC_ACQUIRE, "agent"); // one invalidate/tick
        }
        __syncthreads();

        const u16* aIn; const u16* aHid; u16* hcurb;
        if (!ISL1) {
            aIn   = a.xbf + (size_t)t*B*KIN;
            aHid  = myh0 + (size_t)((t + R0 - 1) & (R0 - 1))*B*H;  // h0[t-1]
            hcurb = myh0 + (size_t)(t & (R0 - 1))*B*H;             // h0[t]
        } else {
            aIn   = myh0 + (size_t)(t & (R0 - 1))*B*H;             // h0[t]
            aHid  = myh1 + (size_t)((t + 1) & 1)*B*H;              // h1[t-1]
            hcurb = myh1 + (size_t)(t & 1)*B*H;                    // h1[t]
        }
        const u16* rowIn[4]; const u16* rowHid[4];
        #pragma unroll
        for (int m = 0; m < 4; ++m) {
            rowIn[m]  = aIn  + (size_t)(m*16 + cix)*LDIN + qo;
            rowHid[m] = aHid + (size_t)(m*16 + cix)*H    + qo;
        }
        f32x4 aR[4], aZ[4], aNI[4], aNH[4];
        #pragma unroll
        for (int m = 0; m < 4; ++m) {
            aR[m]  = f32x4{0,0,0,0}; aZ[m]  = f32x4{0,0,0,0};
            aNI[m] = f32x4{0,0,0,0}; aNH[m] = f32x4{0,0,0,0};
        }
        #pragma unroll
        for (int i = 0; i < NKS; ++i) {
            const int kwg = wv*NKS + i;
            if (kwg < NIW) {
                #pragma unroll
                for (int m = 0; m < 4; ++m) {
                    short8 af = *(const short8*)(rowIn[m] + (size_t)kwg*32);
                    aR[m]  = MFMA16(af, wr[i], aR[m],  0,0,0);
                    aZ[m]  = MFMA16(af, wz[i], aZ[m],  0,0,0);
                    aNI[m] = MFMA16(af, wn[i], aNI[m], 0,0,0);
                }
            } else {
                #pragma unroll
                for (int m = 0; m < 4; ++m) {
                    short8 af = *(const short8*)(rowHid[m] + (size_t)(kwg - NIW)*32);
                    aR[m]  = MFMA16(af, wr[i], aR[m],  0,0,0);
                    aZ[m]  = MFMA16(af, wz[i], aZ[m],  0,0,0);
                    aNH[m] = MFMA16(af, wn[i], aNH[m], 0,0,0);
                }
            }
        }
        // ---- stage 1: waves 4-7 write partials to slot wv-4 ----
        if (wv >= 4) {
            f32x4* pw = red + (size_t)(wv - 4)*1024;
            #pragma unroll
            for (int m = 0; m < 4; ++m) {
                const int cbase = cix*16;
                const int csw   = (m*4 + q) ^ (cix & 7);
                pw[0*256 + cbase + csw] = aR[m];
                pw[1*256 + cbase + csw] = aZ[m];
                pw[2*256 + cbase + csw] = aNI[m];
                pw[3*256 + cbase + csw] = aNH[m];
            }
        }
        __syncthreads();
        // ---- stage 2: waves 0-3 fold partner partials, write 2-way sums ----
        if (wv < 4) {
            f32x4* pw = red + (size_t)wv*1024;
            #pragma unroll
            for (int m = 0; m < 4; ++m) {
                const int cbase = cix*16;
                const int csw   = (m*4 + q) ^ (cix & 7);
                aR[m]  += pw[0*256 + cbase + csw];
                aZ[m]  += pw[1*256 + cbase + csw];
                aNI[m] += pw[2*256 + cbase + csw];
                aNH[m] += pw[3*256 + cbase + csw];
                pw[0*256 + cbase + csw] = aR[m];
                pw[1*256 + cbase + csw] = aZ[m];
                pw[2*256 + cbase + csw] = aNI[m];
                pw[3*256 + cbase + csw] = aNH[m];
            }
        }
        __syncthreads();
        // ---- stage 3: final 4-way sum + elementwise ----
        if (hPath || ISL1) {
            f32x4 sR = {0,0,0,0}, sZ = {0,0,0,0}, sNI = {0,0,0,0}, sNH = {0,0,0,0};
            const int cidx = col*16 + (rq ^ (col & 7));
            #pragma unroll
            for (int ww = 0; ww < 4; ++ww) {
                const f32x4* pr = red + (size_t)ww*1024;
                sR  += pr[0*256 + cidx];
                sZ  += pr[1*256 + cidx];
                sNI += pr[2*256 + cidx];
                sNH += pr[3*256 + cidx];
            }
            #pragma unroll
            for (int v = 0; v < 4; ++v) {
                float r  = 1.f/(1.f + __expf(-(sR[v] + br)));
                float z  = 1.f/(1.f + __expf(-(sZ[v] + bz)));
                float xn = (sNI[v] + bin) + r*(sNH[v] + bhn);
                float e2 = __expf(2.f*xn);
                float n  = 1.f - 2.f/(e2 + 1.f);          // tanh, no inf/inf
                float hn = (1.f - z)*n + z*hp[v];
                hp[v] = hn;                                // both paths stay current
                if (hPath) {
                    // write-through (agent scope): LLC always current, no wb fence
                    __hip_atomic_store(&hcurb[(size_t)(r0 + v)*H + jl], f2bf(hn),
                                       __ATOMIC_RELAXED, __HIP_MEMORY_SCOPE_AGENT);
                } else {  // ISL1, waves 4-7
                    __builtin_nontemporal_store(hn, &a.out[((size_t)(r0+v)*S + t)*(2*H) + dir*H + jl]);
                    if (t == S-1)
                        __builtin_nontemporal_store(hn, &a.out2[(size_t)(r0+v)*(2*H) + dir*H + jl]);
                }
            }
        }
        // ---- publish: drain all waves' stores (vmcnt(0) at barrier), bump own line ----
        __syncthreads();
        if (tid == 0) {
            asm volatile("s_waitcnt vmcnt(0)" ::: "memory");
            __hip_atomic_fetch_add(myline, 1u, __ATOMIC_RELAXED, __HIP_MEMORY_SCOPE_AGENT);
        }
    }
}

// 256 blocks x 512 threads, persistent. block = (cell<<6)|blk; cell 0=0f,1=0b,2=1f,3=1b.
__launch_bounds__(512, 2)
__global__ void gru_persist(PArgs a) {
    __shared__ __align__(16) f32x4 red[4096];   // 64 KB, 2-stage reduce buffer
    const int cell = blockIdx.x >> 6;
    const int blk  = blockIdx.x & 63;
    if (cell == 0) {
        run_cell<6,16,1536,KIN,false>(a, 0, a.wp + (size_t)blk*48*1536,
                                      a.bih0f, a.bhh0f, red);
    } else if (cell == 1) {
        run_cell<6,16,1536,KIN,false>(a, 1, a.wp + WP_ELEMS0 + (size_t)blk*48*1536,
                                      a.bih0b, a.bhh0b, red);
    } else if (cell == 2) {
        run_cell<8,32,2048,H,true>(a, 0, a.wp + 2*WP_ELEMS0 + (size_t)blk*48*2048,
                                   a.bih1f, a.bhh1f, red);
    } else {
        run_cell<8,32,2048,H,true>(a, 1, a.wp + 2*WP_ELEMS0 + WP_ELEMS1 + (size_t)blk*48*2048,
                                   a.bih1b, a.bhh1b, red);
    }
}

extern "C" void kernel_launch(void* const* d_in, const int* in_sizes, int n_in,
                              void* d_out, int out_size, void* d_ws, size_t ws_size,
                              hipStream_t stream) {
    const float* x    = (const float*)d_in[0];
    const float* wi0f = (const float*)d_in[1];
    const float* wh0f = (const float*)d_in[2];
    const float* bi0f = (const float*)d_in[3];
    const float* bh0f = (const float*)d_in[4];
    const float* wi0b = (const float*)d_in[5];
    const float* wh0b = (const float*)d_in[6];
    const float* bi0b = (const float*)d_in[7];
    const float* bh0b = (const float*)d_in[8];
    const float* wi1f = (const float*)d_in[9];
    const float* wh1f = (const float*)d_in[10];
    const float* bi1f = (const float*)d_in[11];
    const float* bh1f = (const float*)d_in[12];
    const float* wi1b = (const float*)d_in[13];
    const float* wh1b = (const float*)d_in[14];
    const float* bi1b = (const float*)d_in[15];
    const float* bh1b = (const float*)d_in[16];

    char* ws = (char*)d_ws;
    hipMemsetAsync(ws, 0, OFF_ZEND, stream);   // progress lines + h states = 0

    u16* xbf = (u16*)(ws + OFF_XBF);
    u16* wp  = (u16*)(ws + OFF_WP);

    pack_w<<<4*64*48, 256, 0, stream>>>(wi0f, wh0f, wi0b, wh0b, wi1f, wh1f, wi1b, wh1b, wp);
    conv_x<<<S*B, 256, 0, stream>>>(x, xbf);

    PArgs a;
    a.wp = wp; a.xbf = xbf;
    a.bih0f = bi0f; a.bhh0f = bh0f; a.bih0b = bi0b; a.bhh0b = bh0b;
    a.bih1f = bi1f; a.bhh1f = bh1f; a.bih1b = bi1b; a.bhh1b = bh1b;
    a.h0bf = (u16*)(ws + OFF_H0BF); a.h1bf = (u16*)(ws + OFF_H1BF);
    a.out  = (float*)d_out;
    a.out2 = (float*)d_out + (size_t)B*S*2*H;
    a.cnt  = (unsigned*)(ws + OFF_CNT);
    gru_persist<<<256, 512, 0, stream>>>(a);
}